// Round 1
// baseline (780.224 us; speedup 1.0000x reference)
//
#include <hip/hip_runtime.h>
#include <hip/hip_bf16.h>

#define M_TOK 16384   // B*S
#define DDIM  1024
#define NEXP  8

typedef __bf16 bf16x8 __attribute__((ext_vector_type(8)));
typedef float  floatx4 __attribute__((ext_vector_type(4)));

__device__ __forceinline__ void gload_lds16(const void* g, void* l) {
    __builtin_amdgcn_global_load_lds(
        (__attribute__((address_space(1))) void*)(void*)g,
        (__attribute__((address_space(3))) void*)l,
        16, 0, 0);
}

// ---------------------------------------------------------------------------
// Kernel 1: route logits + softmax -> rw [M,8] fp32, and h -> bf16
// One wave per token row. W_route staged in LDS (32 KB).
// ---------------------------------------------------------------------------
__global__ __launch_bounds__(256) void route_kernel(
    const float* __restrict__ h, const float* __restrict__ Wr,
    const float* __restrict__ br, __bf16* __restrict__ hbf,
    float* __restrict__ rw)
{
    __shared__ float Wrs[NEXP * DDIM];
    const int tid = threadIdx.x;
    {
        const float4* s4 = (const float4*)Wr;
        float4* d4 = (float4*)Wrs;
        #pragma unroll
        for (int j = 0; j < 8; ++j) d4[j * 256 + tid] = s4[j * 256 + tid];
    }
    __syncthreads();

    const int wave = tid >> 6, lane = tid & 63;
    const int m = blockIdx.x * 4 + wave;

    const float4* hrow = (const float4*)(h + (size_t)m * DDIM + lane * 16);
    float a[16];
    #pragma unroll
    for (int i = 0; i < 4; ++i) {
        float4 v = hrow[i];
        a[i * 4 + 0] = v.x; a[i * 4 + 1] = v.y;
        a[i * 4 + 2] = v.z; a[i * 4 + 3] = v.w;
    }

    // h -> bf16 (RNE via fptrunc)
    bf16x8 o0, o1;
    #pragma unroll
    for (int i = 0; i < 8; ++i) { o0[i] = (__bf16)a[i]; o1[i] = (__bf16)a[8 + i]; }
    *(bf16x8*)(hbf + (size_t)m * DDIM + lane * 16)     = o0;
    *(bf16x8*)(hbf + (size_t)m * DDIM + lane * 16 + 8) = o1;

    // 8 partial dots
    float p[NEXP];
    #pragma unroll
    for (int e = 0; e < NEXP; ++e) {
        const float4* w4 = (const float4*)&Wrs[e * DDIM + lane * 16];
        float s = 0.f;
        #pragma unroll
        for (int i = 0; i < 4; ++i) {
            float4 wv = w4[i];
            s += a[i*4+0]*wv.x + a[i*4+1]*wv.y + a[i*4+2]*wv.z + a[i*4+3]*wv.w;
        }
        p[e] = s;
    }
    // wave-wide butterfly reduce (64 lanes)
    #pragma unroll
    for (int e = 0; e < NEXP; ++e) {
        #pragma unroll
        for (int off = 32; off > 0; off >>= 1)
            p[e] += __shfl_xor(p[e], off, 64);
    }
    if (lane == 0) {
        float l[NEXP], mx = -1e30f;
        #pragma unroll
        for (int e = 0; e < NEXP; ++e) { l[e] = p[e] + br[e]; mx = fmaxf(mx, l[e]); }
        float s = 0.f;
        #pragma unroll
        for (int e = 0; e < NEXP; ++e) { l[e] = expf(l[e] - mx); s += l[e]; }
        float inv = 1.f / s;
        float4 r0 = {l[0]*inv, l[1]*inv, l[2]*inv, l[3]*inv};
        float4 r1 = {l[4]*inv, l[5]*inv, l[6]*inv, l[7]*inv};
        *(float4*)(rw + (size_t)m * NEXP)     = r0;
        *(float4*)(rw + (size_t)m * NEXP + 4) = r1;
    }
}

// ---------------------------------------------------------------------------
// Kernel 2: W_edges fp32 -> bf16, 16 elems/thread
// ---------------------------------------------------------------------------
__global__ __launch_bounds__(256) void convw_kernel(
    const float* __restrict__ src, __bf16* __restrict__ dst)
{
    size_t base = ((size_t)blockIdx.x * 256 + threadIdx.x) * 16;
    const float4* s4 = (const float4*)(src + base);
    float a[16];
    #pragma unroll
    for (int i = 0; i < 4; ++i) {
        float4 v = s4[i];
        a[i*4+0] = v.x; a[i*4+1] = v.y; a[i*4+2] = v.z; a[i*4+3] = v.w;
    }
    bf16x8 o0, o1;
    #pragma unroll
    for (int i = 0; i < 8; ++i) { o0[i] = (__bf16)a[i]; o1[i] = (__bf16)a[8 + i]; }
    *(bf16x8*)(dst + base)     = o0;
    *(bf16x8*)(dst + base + 8) = o1;
}

// ---------------------------------------------------------------------------
// Kernel 3: fused MoE GEMM. Block tile 128x128, BK=64, 4 waves (2x2),
// wave tile 64x64 via 4x4 frags of mfma_f32_16x16x32_bf16.
// Expert-outer loop; per-expert acc scaled by rw and folded into final acc.
// Epilogue: +bias, exact-erf GELU, fp32 store.
// ---------------------------------------------------------------------------
__global__ __launch_bounds__(256, 2) void gemm_moe_kernel(
    const __bf16* __restrict__ hbf, const __bf16* __restrict__ Webf,
    const float* __restrict__ rw, const float* __restrict__ bias,
    float* __restrict__ outp)
{
    __shared__ __bf16 As[128 * 64];
    __shared__ __bf16 Bs[128 * 64];
    __shared__ float  rws[128 * NEXP];

    const int tid  = threadIdx.x;
    const int wave = tid >> 6, lane = tid & 63;
    const int quad = lane >> 4, l16 = lane & 15;
    const int wm = wave & 1, wn = wave >> 1;
    const int m0 = blockIdx.y * 128, f0 = blockIdx.x * 128;

    // stage routing weights for this block's 128 rows (1024 floats)
    {
        const float4* src = (const float4*)(rw + (size_t)m0 * NEXP);
        ((float4*)rws)[tid] = src[tid];
    }

    const floatx4 z4 = {0.f, 0.f, 0.f, 0.f};
    floatx4 facc[4][4];
    #pragma unroll
    for (int i = 0; i < 4; ++i) {
        #pragma unroll
        for (int j = 0; j < 4; ++j) facc[i][j] = z4;
    }

    for (int e = 0; e < NEXP; ++e) {
        const __bf16* Wg = Webf + (size_t)e * DDIM * DDIM;
        floatx4 eacc[4][4];
        #pragma unroll
        for (int i = 0; i < 4; ++i) {
            #pragma unroll
            for (int j = 0; j < 4; ++j) eacc[i][j] = z4;
        }

        for (int k0 = 0; k0 < DDIM; k0 += 64) {
            __syncthreads();  // prior-iter LDS reads done before restage
            #pragma unroll
            for (int t = 0; t < 4; ++t) {
                int g   = t * 256 + tid;
                int row = g >> 3;
                int c   = (g & 7) * 8;
                gload_lds16(hbf + (size_t)(m0 + row) * DDIM + k0 + c, (char*)As + g * 16);
                gload_lds16(Wg  + (size_t)(f0 + row) * DDIM + k0 + c, (char*)Bs + g * 16);
            }
            __syncthreads();  // compiler drains vmcnt before s_barrier

            #pragma unroll
            for (int s = 0; s < 2; ++s) {
                bf16x8 av[4], bv[4];
                #pragma unroll
                for (int mf = 0; mf < 4; ++mf)
                    av[mf] = *(const bf16x8*)&As[(wm*64 + mf*16 + l16)*64 + s*32 + quad*8];
                #pragma unroll
                for (int nf = 0; nf < 4; ++nf)
                    bv[nf] = *(const bf16x8*)&Bs[(wn*64 + nf*16 + l16)*64 + s*32 + quad*8];
                #pragma unroll
                for (int mf = 0; mf < 4; ++mf) {
                    #pragma unroll
                    for (int nf = 0; nf < 4; ++nf)
                        eacc[mf][nf] = __builtin_amdgcn_mfma_f32_16x16x32_bf16(
                            av[mf], bv[nf], eacc[mf][nf], 0, 0, 0);
                }
            }
        }

        // fold expert contribution: facc += rw[m,e] * eacc
        #pragma unroll
        for (int mf = 0; mf < 4; ++mf) {
            #pragma unroll
            for (int r = 0; r < 4; ++r) {
                float w = rws[(wm*64 + mf*16 + quad*4 + r) * NEXP + e];
                #pragma unroll
                for (int nf = 0; nf < 4; ++nf)
                    facc[mf][nf][r] += w * eacc[mf][nf][r];
            }
        }
    }

    // epilogue: bias + exact GELU + store
    #pragma unroll
    for (int nf = 0; nf < 4; ++nf) {
        int gf = f0 + wn*64 + nf*16 + l16;
        float bval = bias[gf];
        #pragma unroll
        for (int mf = 0; mf < 4; ++mf) {
            int gm = m0 + wm*64 + mf*16 + quad*4;
            #pragma unroll
            for (int r = 0; r < 4; ++r) {
                float x = facc[mf][nf][r] + bval;
                float gel = 0.5f * x * (1.0f + erff(x * 0.70710678118f));
                outp[(size_t)(gm + r) * DDIM + gf] = gel;
            }
        }
    }
}

// ---------------------------------------------------------------------------
extern "C" void kernel_launch(void* const* d_in, const int* in_sizes, int n_in,
                              void* d_out, int out_size, void* d_ws, size_t ws_size,
                              hipStream_t stream) {
    const float* h    = (const float*)d_in[0];   // [4,4096,1024]
    const float* Wr   = (const float*)d_in[1];   // [8,1024]
    const float* br   = (const float*)d_in[2];   // [8]
    const float* We   = (const float*)d_in[3];   // [8,1024,1024]
    const float* bias = (const float*)d_in[4];   // [1024]
    float* outp = (float*)d_out;

    char* ws = (char*)d_ws;
    __bf16* hbf  = (__bf16*)ws;                                  // 32 MB
    __bf16* Webf = (__bf16*)(ws + (size_t)M_TOK * DDIM * 2);     // 16 MB
    float*  rwp  = (float*)(ws + (size_t)M_TOK * DDIM * 2
                               + (size_t)NEXP * DDIM * DDIM * 2); // 512 KB

    hipLaunchKernelGGL(route_kernel, dim3(M_TOK / 4), dim3(256), 0, stream,
                       h, Wr, br, hbf, rwp);
    hipLaunchKernelGGL(convw_kernel, dim3((NEXP * DDIM * DDIM) / (256 * 16)),
                       dim3(256), 0, stream, We, Webf);
    hipLaunchKernelGGL(gemm_moe_kernel, dim3(DDIM / 128, M_TOK / 128),
                       dim3(256), 0, stream, hbf, Webf, rwp, bias, outp);
}

// Round 2
// 761.724 us; speedup vs baseline: 1.0243x; 1.0243x over previous
//
#include <hip/hip_runtime.h>
#include <hip/hip_bf16.h>

#define M_TOK 16384   // B*S
#define DDIM  1024
#define NEXP  8

typedef __bf16 bf16x8 __attribute__((ext_vector_type(8)));
typedef float  floatx4 __attribute__((ext_vector_type(4)));

__device__ __forceinline__ void gload_lds16(const void* g, void* l) {
    __builtin_amdgcn_global_load_lds(
        (__attribute__((address_space(1))) void*)(void*)g,
        (__attribute__((address_space(3))) void*)l,
        16, 0, 0);
}

// ---------------------------------------------------------------------------
// Kernel 1: route logits + softmax -> rw [M,8] fp32, and h -> bf16
// One wave per token row. W_route staged in LDS (32 KB).
// ---------------------------------------------------------------------------
__global__ __launch_bounds__(256) void route_kernel(
    const float* __restrict__ h, const float* __restrict__ Wr,
    const float* __restrict__ br, __bf16* __restrict__ hbf,
    float* __restrict__ rw)
{
    __shared__ float Wrs[NEXP * DDIM];
    const int tid = threadIdx.x;
    {
        const float4* s4 = (const float4*)Wr;
        float4* d4 = (float4*)Wrs;
        #pragma unroll
        for (int j = 0; j < 8; ++j) d4[j * 256 + tid] = s4[j * 256 + tid];
    }
    __syncthreads();

    const int wave = tid >> 6, lane = tid & 63;
    const int m = blockIdx.x * 4 + wave;

    const float4* hrow = (const float4*)(h + (size_t)m * DDIM + lane * 16);
    float a[16];
    #pragma unroll
    for (int i = 0; i < 4; ++i) {
        float4 v = hrow[i];
        a[i * 4 + 0] = v.x; a[i * 4 + 1] = v.y;
        a[i * 4 + 2] = v.z; a[i * 4 + 3] = v.w;
    }

    // h -> bf16 (RNE via fptrunc)
    bf16x8 o0, o1;
    #pragma unroll
    for (int i = 0; i < 8; ++i) { o0[i] = (__bf16)a[i]; o1[i] = (__bf16)a[8 + i]; }
    *(bf16x8*)(hbf + (size_t)m * DDIM + lane * 16)     = o0;
    *(bf16x8*)(hbf + (size_t)m * DDIM + lane * 16 + 8) = o1;

    // 8 partial dots
    float p[NEXP];
    #pragma unroll
    for (int e = 0; e < NEXP; ++e) {
        const float4* w4 = (const float4*)&Wrs[e * DDIM + lane * 16];
        float s = 0.f;
        #pragma unroll
        for (int i = 0; i < 4; ++i) {
            float4 wv = w4[i];
            s += a[i*4+0]*wv.x + a[i*4+1]*wv.y + a[i*4+2]*wv.z + a[i*4+3]*wv.w;
        }
        p[e] = s;
    }
    // wave-wide butterfly reduce (64 lanes)
    #pragma unroll
    for (int e = 0; e < NEXP; ++e) {
        #pragma unroll
        for (int off = 32; off > 0; off >>= 1)
            p[e] += __shfl_xor(p[e], off, 64);
    }
    if (lane == 0) {
        float l[NEXP], mx = -1e30f;
        #pragma unroll
        for (int e = 0; e < NEXP; ++e) { l[e] = p[e] + br[e]; mx = fmaxf(mx, l[e]); }
        float s = 0.f;
        #pragma unroll
        for (int e = 0; e < NEXP; ++e) { l[e] = expf(l[e] - mx); s += l[e]; }
        float inv = 1.f / s;
        float4 r0 = {l[0]*inv, l[1]*inv, l[2]*inv, l[3]*inv};
        float4 r1 = {l[4]*inv, l[5]*inv, l[6]*inv, l[7]*inv};
        *(float4*)(rw + (size_t)m * NEXP)     = r0;
        *(float4*)(rw + (size_t)m * NEXP + 4) = r1;
    }
}

// ---------------------------------------------------------------------------
// Kernel 2: W_edges fp32 -> bf16, 16 elems/thread
// ---------------------------------------------------------------------------
__global__ __launch_bounds__(256) void convw_kernel(
    const float* __restrict__ src, __bf16* __restrict__ dst)
{
    size_t base = ((size_t)blockIdx.x * 256 + threadIdx.x) * 16;
    const float4* s4 = (const float4*)(src + base);
    float a[16];
    #pragma unroll
    for (int i = 0; i < 4; ++i) {
        float4 v = s4[i];
        a[i*4+0] = v.x; a[i*4+1] = v.y; a[i*4+2] = v.z; a[i*4+3] = v.w;
    }
    bf16x8 o0, o1;
    #pragma unroll
    for (int i = 0; i < 8; ++i) { o0[i] = (__bf16)a[i]; o1[i] = (__bf16)a[8 + i]; }
    *(bf16x8*)(dst + base)     = o0;
    *(bf16x8*)(dst + base + 8) = o1;
}

// ---------------------------------------------------------------------------
// Kernel 3: fused MoE GEMM. Block tile 128x128, BK=64, 4 waves (2x2),
// wave tile 64x64 via 4x4 frags of mfma_f32_16x16x32_bf16.
// LDS layout XOR-swizzled at 16B granularity: slot g holds global
// (row=g>>3, grp=(g&7)^(row&7)); reader slot = r*8 + ((grp^r)&7).
// Quad's 16 lanes then span all 32 banks at 2-way aliasing (free, m136),
// vs 16-way conflict for the linear layout (128B row stride = bank period).
// ---------------------------------------------------------------------------
__global__ __launch_bounds__(256, 2) void gemm_moe_kernel(
    const __bf16* __restrict__ hbf, const __bf16* __restrict__ Webf,
    const float* __restrict__ rw, const float* __restrict__ bias,
    float* __restrict__ outp)
{
    __shared__ __bf16 As[128 * 64];
    __shared__ __bf16 Bs[128 * 64];
    __shared__ float  rws[128 * NEXP];

    const int tid  = threadIdx.x;
    const int wave = tid >> 6, lane = tid & 63;
    const int quad = lane >> 4, l16 = lane & 15;
    const int wm = wave & 1, wn = wave >> 1;
    const int m0 = blockIdx.y * 128, f0 = blockIdx.x * 128;

    // stage routing weights for this block's 128 rows (1024 floats)
    {
        const float4* src = (const float4*)(rw + (size_t)m0 * NEXP);
        ((float4*)rws)[tid] = src[tid];
    }

    const floatx4 z4 = {0.f, 0.f, 0.f, 0.f};
    floatx4 facc[4][4];
    #pragma unroll
    for (int i = 0; i < 4; ++i) {
        #pragma unroll
        for (int j = 0; j < 4; ++j) facc[i][j] = z4;
    }

    // precomputed swizzled read slots (independent of k0/e)
    // A rows: wm*64 + mf*16 + l16 ; B rows: wn*64 + nf*16 + l16
    int aslot[2][4], bslot[2][4];
    #pragma unroll
    for (int s = 0; s < 2; ++s) {
        #pragma unroll
        for (int f = 0; f < 4; ++f) {
            int ra = wm*64 + f*16 + l16;
            int rb = wn*64 + f*16 + l16;
            int grp = s*4 + quad;
            aslot[s][f] = ra*8 + ((grp ^ ra) & 7);
            bslot[s][f] = rb*8 + ((grp ^ rb) & 7);
        }
    }

    for (int e = 0; e < NEXP; ++e) {
        const __bf16* Wg = Webf + (size_t)e * DDIM * DDIM;
        floatx4 eacc[4][4];
        #pragma unroll
        for (int i = 0; i < 4; ++i) {
            #pragma unroll
            for (int j = 0; j < 4; ++j) eacc[i][j] = z4;
        }

        for (int k0 = 0; k0 < DDIM; k0 += 64) {
            __syncthreads();  // prior-iter LDS reads done before restage
            #pragma unroll
            for (int t = 0; t < 4; ++t) {
                int g   = t * 256 + tid;
                int row = g >> 3;
                int c   = ((g ^ row) & 7) * 8;   // swizzled column group
                gload_lds16(hbf + (size_t)(m0 + row) * DDIM + k0 + c, (char*)As + g * 16);
                gload_lds16(Wg  + (size_t)(f0 + row) * DDIM + k0 + c, (char*)Bs + g * 16);
            }
            __syncthreads();  // compiler drains vmcnt before s_barrier

            #pragma unroll
            for (int s = 0; s < 2; ++s) {
                bf16x8 av[4], bv[4];
                #pragma unroll
                for (int mf = 0; mf < 4; ++mf)
                    av[mf] = *(const bf16x8*)&As[aslot[s][mf] * 8];
                #pragma unroll
                for (int nf = 0; nf < 4; ++nf)
                    bv[nf] = *(const bf16x8*)&Bs[bslot[s][nf] * 8];
                #pragma unroll
                for (int mf = 0; mf < 4; ++mf) {
                    #pragma unroll
                    for (int nf = 0; nf < 4; ++nf)
                        eacc[mf][nf] = __builtin_amdgcn_mfma_f32_16x16x32_bf16(
                            av[mf], bv[nf], eacc[mf][nf], 0, 0, 0);
                }
            }
        }

        // fold expert contribution: facc += rw[m,e] * eacc
        // (rws read is quad-uniform -> LDS broadcast, conflict-free)
        #pragma unroll
        for (int mf = 0; mf < 4; ++mf) {
            #pragma unroll
            for (int r = 0; r < 4; ++r) {
                float w = rws[(wm*64 + mf*16 + quad*4 + r) * NEXP + e];
                #pragma unroll
                for (int nf = 0; nf < 4; ++nf)
                    facc[mf][nf][r] += w * eacc[mf][nf][r];
            }
        }
    }

    // epilogue: bias + exact GELU + store
    #pragma unroll
    for (int nf = 0; nf < 4; ++nf) {
        int gf = f0 + wn*64 + nf*16 + l16;
        float bval = bias[gf];
        #pragma unroll
        for (int mf = 0; mf < 4; ++mf) {
            int gm = m0 + wm*64 + mf*16 + quad*4;
            #pragma unroll
            for (int r = 0; r < 4; ++r) {
                float x = facc[mf][nf][r] + bval;
                float gel = 0.5f * x * (1.0f + erff(x * 0.70710678118f));
                outp[(size_t)(gm + r) * DDIM + gf] = gel;
            }
        }
    }
}

// ---------------------------------------------------------------------------
extern "C" void kernel_launch(void* const* d_in, const int* in_sizes, int n_in,
                              void* d_out, int out_size, void* d_ws, size_t ws_size,
                              hipStream_t stream) {
    const float* h    = (const float*)d_in[0];   // [4,4096,1024]
    const float* Wr   = (const float*)d_in[1];   // [8,1024]
    const float* br   = (const float*)d_in[2];   // [8]
    const float* We   = (const float*)d_in[3];   // [8,1024,1024]
    const float* bias = (const float*)d_in[4];   // [1024]
    float* outp = (float*)d_out;

    char* ws = (char*)d_ws;
    __bf16* hbf  = (__bf16*)ws;                                  // 32 MB
    __bf16* Webf = (__bf16*)(ws + (size_t)M_TOK * DDIM * 2);     // 16 MB
    float*  rwp  = (float*)(ws + (size_t)M_TOK * DDIM * 2
                               + (size_t)NEXP * DDIM * DDIM * 2); // 512 KB

    hipLaunchKernelGGL(route_kernel, dim3(M_TOK / 4), dim3(256), 0, stream,
                       h, Wr, br, hbf, rwp);
    hipLaunchKernelGGL(convw_kernel, dim3((NEXP * DDIM * DDIM) / (256 * 16)),
                       dim3(256), 0, stream, We, Webf);
    hipLaunchKernelGGL(gemm_moe_kernel, dim3(DDIM / 128, M_TOK / 128),
                       dim3(256), 0, stream, hbf, Webf, rwp, bias, outp);
}